// Round 2
// baseline (5323.224 us; speedup 1.0000x reference)
//
#include <hip/hip_runtime.h>
#include <hip/hip_cooperative_groups.h>

namespace cg = cooperative_groups;

typedef short s16x8 __attribute__((ext_vector_type(8)));
typedef float f32x4 __attribute__((ext_vector_type(4)));
typedef unsigned int u32x4 __attribute__((ext_vector_type(4)));
typedef unsigned int u32x2 __attribute__((ext_vector_type(2)));

#define B_ 64
#define T_ 512
#define D_ 1024
#define H_ 1024
#define TC_ 128   // time chunk

__device__ __forceinline__ unsigned short f2bf(float f) {
  union { float f; unsigned int u; } v; v.f = f;
  unsigned int r = v.u + 0x7fffu + ((v.u >> 16) & 1u);
  return (unsigned short)(r >> 16);
}
__device__ __forceinline__ float bf2f(unsigned short h) {
  union { unsigned int u; float f; } v; v.u = ((unsigned int)h) << 16;
  return v.f;
}

// ---- convert W_ih and W_hh fp32 -> bf16 (n = 3*1024*1024 each) ----
__global__ __launch_bounds__(256) void k_cvt_w(const float* __restrict__ w1, unsigned short* __restrict__ o1,
                                               const float* __restrict__ w2, unsigned short* __restrict__ o2) {
  int i = (blockIdx.x * 256 + threadIdx.x) * 4;
  float4 a = *(const float4*)(w1 + i);
  u32x2 p;
  p.x = (unsigned)f2bf(a.x) | ((unsigned)f2bf(a.y) << 16);
  p.y = (unsigned)f2bf(a.z) | ((unsigned)f2bf(a.w) << 16);
  *(u32x2*)(o1 + i) = p;
  float4 b = *(const float4*)(w2 + i);
  u32x2 q;
  q.x = (unsigned)f2bf(b.x) | ((unsigned)f2bf(b.y) << 16);
  q.y = (unsigned)f2bf(b.z) | ((unsigned)f2bf(b.w) << 16);
  *(u32x2*)(o2 + i) = q;
}

// ---- x [B][T][D] fp32 -> xt [(tl*64+b)][D] bf16 for t in [t0, t0+TC_) ----
__global__ __launch_bounds__(256) void k_xt(const float* __restrict__ x, unsigned short* __restrict__ xt, int t0) {
  int m = blockIdx.x;              // m = tl*64 + b, tl in [0,TC_)
  int t = t0 + (m >> 6), b = m & 63;
  const float* src = x + ((size_t)(b * T_ + t)) * D_;
  unsigned short* dst = xt + (size_t)m * D_;
  int d = threadIdx.x * 4;
  float4 a = *(const float4*)(src + d);
  u32x2 p;
  p.x = (unsigned)f2bf(a.x) | ((unsigned)f2bf(a.y) << 16);
  p.y = (unsigned)f2bf(a.z) | ((unsigned)f2bf(a.w) << 16);
  *(u32x2*)(dst + d) = p;
}

// ---- h0 -> hbuf16[0] (bf16) + hchk (fp32); dones [B][T] -> maskT [T][B] float; zero barrier ----
__global__ __launch_bounds__(256) void k_misc(const float* __restrict__ h0, const int* __restrict__ dones,
                                              unsigned short* __restrict__ hb16, float* __restrict__ hchk,
                                              float* __restrict__ maskT, unsigned int* __restrict__ bar) {
  int i = blockIdx.x * 256 + threadIdx.x;  // 65536 threads = B*H
  float v = h0[i];
  hb16[i] = f2bf(v);
  hchk[i] = v;
  if (i < T_ * B_) {
    int t = i >> 6, b = i & 63;
    maskT[i] = dones[b * T_ + t] ? 0.f : 1.f;
  }
  if (i == 0) *bar = 0u;
}

// ---- gi = xt @ W_ih^T + b_ih ; A[M=8192][K=1024], B[N=3072][K=1024], C[m][n] bf16 ----
__global__ __launch_bounds__(256) void k_gemm(const unsigned short* __restrict__ A,
                                              const unsigned short* __restrict__ Bm,
                                              const float* __restrict__ bias,
                                              unsigned short* __restrict__ C) {
  __shared__ __align__(16) unsigned short As[128 * 40];  // 32 k-shorts + 8 pad (2-way aliasing: free)
  __shared__ __align__(16) unsigned short Bs[128 * 40];
  const int tid = threadIdx.x;
  const int wave = tid >> 6, lane = tid & 63;
  const int q = lane >> 4, r = lane & 15;
  const int wm = wave >> 1, wn = wave & 1;
  const long m0 = (long)blockIdx.y * 128, n0 = (long)blockIdx.x * 128;
  f32x4 acc[4][4] = {};
  for (int k0 = 0; k0 < 1024; k0 += 32) {
    __syncthreads();
#pragma unroll
    for (int c0 = 0; c0 < 2; ++c0) {
      int c = c0 * 256 + tid;          // 512 16B-chunks (8 shorts each) per tile pair
      int row = c >> 2, kof = (c & 3) * 8;
      *(u32x4*)&As[row * 40 + kof] = *(const u32x4*)(A + (m0 + row) * 1024 + k0 + kof);
      *(u32x4*)&Bs[row * 40 + kof] = *(const u32x4*)(Bm + (n0 + row) * 1024 + k0 + kof);
    }
    __syncthreads();
    s16x8 af[4], bfr[4];
#pragma unroll
    for (int mt = 0; mt < 4; ++mt)
      af[mt] = *(const s16x8*)&As[(wm * 64 + mt * 16 + r) * 40 + q * 8];
#pragma unroll
    for (int nt = 0; nt < 4; ++nt)
      bfr[nt] = *(const s16x8*)&Bs[(wn * 64 + nt * 16 + r) * 40 + q * 8];
#pragma unroll
    for (int mt = 0; mt < 4; ++mt)
#pragma unroll
      for (int nt = 0; nt < 4; ++nt)
        acc[mt][nt] = __builtin_amdgcn_mfma_f32_16x16x32_bf16(af[mt], bfr[nt], acc[mt][nt], 0, 0, 0);
  }
#pragma unroll
  for (int nt = 0; nt < 4; ++nt) {
    long n = n0 + wn * 64 + nt * 16 + r;
    float bn = bias[n];
#pragma unroll
    for (int mt = 0; mt < 4; ++mt) {
#pragma unroll
      for (int reg = 0; reg < 4; ++reg) {
        long m = m0 + wm * 64 + mt * 16 + q * 4 + reg;  // C/D: col=lane&15, row=quad*4+reg
        C[m * 3072 + n] = f2bf(acc[mt][nt][reg] + bn);
      }
    }
  }
}

// ---- persistent recurrent kernel over one time chunk: 64 blocks x 256 threads ----
// block owns output cols j0..j0+15 (all 3 gates); W_hh slice resident in LDS.
// Custom lightweight grid barrier (monotonic counter) replaces threadfence+grid.sync.
__global__ __launch_bounds__(256) void k_gru(const unsigned short* __restrict__ whh,
                                             const float* __restrict__ bhh,
                                             const unsigned short* __restrict__ gi,
                                             const float* __restrict__ maskT,
                                             unsigned short* __restrict__ hb16,
                                             float* __restrict__ hchk,
                                             float* __restrict__ out,
                                             unsigned int* __restrict__ bar,
                                             int t0) {
  __shared__ __align__(16) unsigned short Ws[3][16][1032];  // ~97 KB; +8 pad (2-way aliasing: free)
  const int tid = threadIdx.x;
  const int wave = tid >> 6, lane = tid & 63;
  const int q = lane >> 4, r = lane & 15;
  const int j0 = blockIdx.x * 16;
  float* hlast = out + (size_t)B_ * T_ * H_;

  // stage W_hh rows {g*1024 + j0..j0+15} into LDS once per chunk.
  for (int idx = tid; idx < 48 * 128; idx += 256) {
    int row = idx >> 7, seg = idx & 127;
    int g = row >> 4, l = row & 15;
    *(u32x4*)&Ws[g][l][seg * 8] =
        *(const u32x4*)(whh + ((size_t)(g * 1024 + j0 + l)) * 1024 + seg * 8);
  }
  const float bhr = bhh[j0 + r];
  const float bhz = bhh[1024 + j0 + r];
  const float bhn = bhh[2048 + j0 + r];
  // register-resident fp32 h: the 4 cells (b = wave*16+q*4+reg, col j0+r) this
  // thread updates are exactly the cells it reads next step -> no global fp32 h.
  float hreg[4];
#pragma unroll
  for (int reg = 0; reg < 4; ++reg)
    hreg[reg] = hchk[(size_t)(wave * 16 + q * 4 + reg) * 1024 + j0 + r];
  __syncthreads();

  for (int tl = 0; tl < TC_; ++tl) {
    const int t = t0 + tl;
    const unsigned short* hs16 = hb16 + (size_t)(t & 1) * (B_ * H_);
    unsigned short* hd16 = hb16 + (size_t)((t + 1) & 1) * (B_ * H_);

    // prefetch gi + masks now; their L3 latency hides under the matvec below
    float gir[4], giz[4], gin[4], mb[4];
#pragma unroll
    for (int reg = 0; reg < 4; ++reg) {
      int b = wave * 16 + q * 4 + reg;
      size_t mrow = (size_t)(tl * 64 + b) * 3072;
      gir[reg] = bf2f(gi[mrow + j0 + r]);
      giz[reg] = bf2f(gi[mrow + 1024 + j0 + r]);
      gin[reg] = bf2f(gi[mrow + 2048 + j0 + r]);
      mb[reg] = maskT[t * 64 + b];
    }
    const float mk = maskT[t * 64 + wave * 16 + r];  // mask for A-row b = wave*16 + r

    f32x4 acc0 = {0.f, 0.f, 0.f, 0.f};
    f32x4 acc1 = {0.f, 0.f, 0.f, 0.f};
    f32x4 acc2 = {0.f, 0.f, 0.f, 0.f};
    const unsigned short* arow = hs16 + (size_t)(wave * 16 + r) * 1024;
#pragma unroll 4
    for (int ks = 0; ks < 32; ++ks) {
      u32x4 av = *(const u32x4*)(arow + ks * 32 + q * 8);
      if (mk == 0.f) { av.x = 0; av.y = 0; av.z = 0; av.w = 0; }  // h_eff = h*mask feeds matvec
      s16x8 a = __builtin_bit_cast(s16x8, av);
      s16x8 b0 = *(const s16x8*)&Ws[0][r][ks * 32 + q * 8];
      s16x8 b1 = *(const s16x8*)&Ws[1][r][ks * 32 + q * 8];
      s16x8 b2 = *(const s16x8*)&Ws[2][r][ks * 32 + q * 8];
      acc0 = __builtin_amdgcn_mfma_f32_16x16x32_bf16(a, b0, acc0, 0, 0, 0);
      acc1 = __builtin_amdgcn_mfma_f32_16x16x32_bf16(a, b1, acc1, 0, 0, 0);
      acc2 = __builtin_amdgcn_mfma_f32_16x16x32_bf16(a, b2, acc2, 0, 0, 0);
    }
#pragma unroll
    for (int reg = 0; reg < 4; ++reg) {
      int b = wave * 16 + q * 4 + reg;       // C/D: col=lane&15, row=quad*4+reg
      float ghr = acc0[reg] + bhr;
      float ghz = acc1[reg] + bhz;
      float ghn = acc2[reg] + bhn;
      float rr = 1.f / (1.f + __expf(-(gir[reg] + ghr)));
      float zz = 1.f / (1.f + __expf(-(giz[reg] + ghz)));
      float nn = tanhf(gin[reg] + rr * ghn);
      float hp = hreg[reg] * mb[reg];        // fp32 h for the update path (register-resident)
      float hn = (1.f - zz) * nn + zz * hp;
      out[((size_t)b * 512 + t) * 1024 + j0 + r] = hn;
      hd16[(size_t)b * 1024 + j0 + r] = f2bf(hn);
      hreg[reg] = hn;
      if (t == 511) hlast[(size_t)b * 1024 + j0 + r] = hn;
      if (tl == TC_ - 1) hchk[(size_t)b * 1024 + j0 + r] = hn;  // persist across chunk launches
    }

    // ---- lightweight grid barrier ----
    // __syncthreads drains each thread's vmem (stores reached L2) before the
    // release-RMW; the agent-scope release writes back this XCD's L2 so other
    // XCDs can observe hd16; acquire-load invalidates before next step's reads.
    __syncthreads();
    if (tid == 0) {
      __hip_atomic_fetch_add(bar, 1u, __ATOMIC_RELEASE, __HIP_MEMORY_SCOPE_AGENT);
      const unsigned int target = 64u * (unsigned int)(t + 1);
      while (__hip_atomic_load(bar, __ATOMIC_RELAXED, __HIP_MEMORY_SCOPE_AGENT) < target)
        __builtin_amdgcn_s_sleep(1);
      (void)__hip_atomic_load(bar, __ATOMIC_ACQUIRE, __HIP_MEMORY_SCOPE_AGENT);
    }
    __syncthreads();
  }
}

extern "C" void kernel_launch(void* const* d_in, const int* in_sizes, int n_in,
                              void* d_out, int out_size, void* d_ws, size_t ws_size,
                              hipStream_t stream) {
  const float* x     = (const float*)d_in[0];
  const float* h0    = (const float*)d_in[1];
  const int*   dones = (const int*)d_in[2];
  const float* Wih   = (const float*)d_in[3];
  const float* Whh   = (const float*)d_in[4];
  const float* bih   = (const float*)d_in[5];
  const float* bhh   = (const float*)d_in[6];
  float* out = (float*)d_out;
  char* ws = (char*)d_ws;
  // ws layout (total ~76.6 MiB):
  unsigned short* wih_b = (unsigned short*)(ws);                  //  6 MB   [0, 6291456)
  unsigned short* whh_b = (unsigned short*)(ws + 6291456);        //  6 MB   [6291456, 12582912)
  unsigned short* xt_c  = (unsigned short*)(ws + 12582912);       // 16 MB   [12582912, 29360128)
  unsigned short* gi_c  = (unsigned short*)(ws + 29360128);       // 48 MB   [29360128, 79691776)
  float*          maskT = (float*)(ws + 79691776);                // 128 KB  [79691776, 79822848)
  unsigned short* hb16  = (unsigned short*)(ws + 79822848);       // 256 KB  [79822848, 80085248)
  float*          hchk  = (float*)(ws + 80085248);                // 256 KB  [80085248, 80347392)
  unsigned int*   bar   = (unsigned int*)(ws + 80347392);         // 4 B     AFTER hchk (r1 fix: was overlapping hchk)

  k_cvt_w<<<3072, 256, 0, stream>>>(Wih, wih_b, Whh, whh_b);
  k_misc<<<256, 256, 0, stream>>>(h0, dones, hb16, hchk, maskT, bar);

  for (int c = 0; c < 4; ++c) {
    int t0 = c * TC_;
    k_xt<<<TC_ * 64, 256, 0, stream>>>(x, xt_c, t0);
    k_gemm<<<dim3(24, TC_ * 64 / 128), 256, 0, stream>>>(xt_c, wih_b, bih, gi_c);
    void* args[] = {(void*)&whh_b, (void*)&bhh, (void*)&gi_c, (void*)&maskT,
                    (void*)&hb16, (void*)&hchk, (void*)&out, (void*)&bar, (void*)&t0};
    hipLaunchCooperativeKernel((const void*)k_gru, dim3(64), dim3(256), args, 0, stream);
  }
}

// Round 3
// 4557.795 us; speedup vs baseline: 1.1679x; 1.1679x over previous
//
#include <hip/hip_runtime.h>
#include <hip/hip_cooperative_groups.h>

typedef short s16x8 __attribute__((ext_vector_type(8)));
typedef float f32x4 __attribute__((ext_vector_type(4)));
typedef float f32x2 __attribute__((ext_vector_type(2)));
typedef unsigned int u32x4 __attribute__((ext_vector_type(4)));
typedef unsigned int u32x2 __attribute__((ext_vector_type(2)));

#define B_ 64
#define T_ 512
#define D_ 1024
#define H_ 1024
#define TC_ 128   // time chunk

__device__ __forceinline__ unsigned short f2bf(float f) {
  union { float f; unsigned int u; } v; v.f = f;
  unsigned int r = v.u + 0x7fffu + ((v.u >> 16) & 1u);
  return (unsigned short)(r >> 16);
}
__device__ __forceinline__ float bf2f(unsigned short h) {
  union { unsigned int u; float f; } v; v.u = ((unsigned int)h) << 16;
  return v.f;
}

// async global->LDS, 16B per lane; LDS dest must be wave-uniform base (HW adds lane*16)
__device__ __forceinline__ void g2l16(const unsigned short* g, unsigned short* l) {
  __builtin_amdgcn_global_load_lds((const __attribute__((address_space(1))) unsigned int*)g,
                                   (__attribute__((address_space(3))) unsigned int*)l, 16, 0, 0);
}

// tiled h layout: addr(b,k) = ((b>>4)*32 + (k>>5))*512 + (b&15)*32 + (k&31)
__device__ __forceinline__ int haddr(int b, int k) {
  return (((b >> 4) * 32 + (k >> 5)) << 9) + ((b & 15) << 5) + (k & 31);
}

// ---- convert W_ih and W_hh fp32 -> bf16 (n = 3*1024*1024 each) ----
__global__ __launch_bounds__(256) void k_cvt_w(const float* __restrict__ w1, unsigned short* __restrict__ o1,
                                               const float* __restrict__ w2, unsigned short* __restrict__ o2) {
  int i = (blockIdx.x * 256 + threadIdx.x) * 4;
  float4 a = *(const float4*)(w1 + i);
  u32x2 p;
  p.x = (unsigned)f2bf(a.x) | ((unsigned)f2bf(a.y) << 16);
  p.y = (unsigned)f2bf(a.z) | ((unsigned)f2bf(a.w) << 16);
  *(u32x2*)(o1 + i) = p;
  float4 b = *(const float4*)(w2 + i);
  u32x2 q;
  q.x = (unsigned)f2bf(b.x) | ((unsigned)f2bf(b.y) << 16);
  q.y = (unsigned)f2bf(b.z) | ((unsigned)f2bf(b.w) << 16);
  *(u32x2*)(o2 + i) = q;
}

// ---- x [B][T][D] fp32 -> xt [(tl*64+b)][D] bf16 for t in [t0, t0+TC_) ----
__global__ __launch_bounds__(256) void k_xt(const float* __restrict__ x, unsigned short* __restrict__ xt, int t0) {
  int m = blockIdx.x;              // m = tl*64 + b
  int t = t0 + (m >> 6), b = m & 63;
  const float* src = x + ((size_t)(b * T_ + t)) * D_;
  unsigned short* dst = xt + (size_t)m * D_;
  int d = threadIdx.x * 4;
  float4 a = *(const float4*)(src + d);
  u32x2 p;
  p.x = (unsigned)f2bf(a.x) | ((unsigned)f2bf(a.y) << 16);
  p.y = (unsigned)f2bf(a.z) | ((unsigned)f2bf(a.w) << 16);
  *(u32x2*)(dst + d) = p;
}

// ---- h0 -> hb16T[0] (bf16, TILED, pre-masked for t=0) + hchk (fp32); maskT; zero bar/flag ----
__global__ __launch_bounds__(256) void k_misc(const float* __restrict__ h0, const int* __restrict__ dones,
                                              unsigned short* __restrict__ hb16T, float* __restrict__ hchk,
                                              float* __restrict__ maskT, unsigned int* __restrict__ bar,
                                              unsigned int* __restrict__ flag) {
  int i = blockIdx.x * 256 + threadIdx.x;  // 65536 = B*H
  int b = i >> 10, k = i & 1023;
  float v = h0[i];
  hchk[i] = v;
  int m0 = dones[b * T_];                  // dones[b][0]: h zeroed before consuming step 0
  hb16T[haddr(b, k)] = m0 ? (unsigned short)0 : f2bf(v);
  if (i < T_ * B_) {
    int t = i >> 6, bb = i & 63;
    maskT[i] = dones[bb * T_ + t] ? 0.f : 1.f;
  }
  if (i == 0) { *bar = 0u; *flag = 0u; }
}

// ---- gi = xt @ W_ih^T + b_ih ; A[8192][1024], B[3072][1024], C[m][n] bf16 ----
__global__ __launch_bounds__(256) void k_gemm(const unsigned short* __restrict__ A,
                                              const unsigned short* __restrict__ Bm,
                                              const float* __restrict__ bias,
                                              unsigned short* __restrict__ C) {
  __shared__ __align__(16) unsigned short As[128 * 40];
  __shared__ __align__(16) unsigned short Bs[128 * 40];
  const int tid = threadIdx.x;
  const int wave = tid >> 6, lane = tid & 63;
  const int q = lane >> 4, r = lane & 15;
  const int wm = wave >> 1, wn = wave & 1;
  const long m0 = (long)blockIdx.y * 128, n0 = (long)blockIdx.x * 128;
  f32x4 acc[4][4] = {};
  for (int k0 = 0; k0 < 1024; k0 += 32) {
    __syncthreads();
#pragma unroll
    for (int c0 = 0; c0 < 2; ++c0) {
      int c = c0 * 256 + tid;
      int row = c >> 2, kof = (c & 3) * 8;
      *(u32x4*)&As[row * 40 + kof] = *(const u32x4*)(A + (m0 + row) * 1024 + k0 + kof);
      *(u32x4*)&Bs[row * 40 + kof] = *(const u32x4*)(Bm + (n0 + row) * 1024 + k0 + kof);
    }
    __syncthreads();
    s16x8 af[4], bfr[4];
#pragma unroll
    for (int mt = 0; mt < 4; ++mt)
      af[mt] = *(const s16x8*)&As[(wm * 64 + mt * 16 + r) * 40 + q * 8];
#pragma unroll
    for (int nt = 0; nt < 4; ++nt)
      bfr[nt] = *(const s16x8*)&Bs[(wn * 64 + nt * 16 + r) * 40 + q * 8];
#pragma unroll
    for (int mt = 0; mt < 4; ++mt)
#pragma unroll
      for (int nt = 0; nt < 4; ++nt)
        acc[mt][nt] = __builtin_amdgcn_mfma_f32_16x16x32_bf16(af[mt], bfr[nt], acc[mt][nt], 0, 0, 0);
  }
#pragma unroll
  for (int nt = 0; nt < 4; ++nt) {
    long n = n0 + wn * 64 + nt * 16 + r;
    float bn = bias[n];
#pragma unroll
    for (int mt = 0; mt < 4; ++mt) {
#pragma unroll
      for (int reg = 0; reg < 4; ++reg) {
        long m = m0 + wm * 64 + mt * 16 + q * 4 + reg;
        C[m * 3072 + n] = f2bf(acc[mt][nt][reg] + bn);
      }
    }
  }
}

// ---- persistent recurrent kernel: 64 blocks x 512 threads (8 waves, 2/SIMD) ----
// wave w owns K-slice [w*128,(w+1)*128); W_hh B-frags live in VGPRs all chunk.
// per step: stage tiled h -> LDS (global_load_lds) -> MFMA partials -> LDS kp-reduce
// -> epilogue (2 cells/lane) -> flag barrier (out stores + prefetch overlap the wait).
__global__ __launch_bounds__(512, 2) void k_gru(const unsigned short* __restrict__ whh,
                                                const float* __restrict__ bhh,
                                                const unsigned short* __restrict__ gi,
                                                const float* __restrict__ maskT,
                                                unsigned short* __restrict__ hb16T,
                                                float* __restrict__ hchk,
                                                float* __restrict__ out,
                                                unsigned int* __restrict__ bar,
                                                unsigned int* __restrict__ flag,
                                                int t0) {
  __shared__ __align__(16) unsigned char smem[131072];
  unsigned short* lds_h = (unsigned short*)smem;  // 65536 bf16, tiled h
  float* red = (float*)smem;                      // ALIASED: partials [3][8][16][68] (104 KB) — barrier-guarded
  const int tid = threadIdx.x;
  const int w = tid >> 6, lane = tid & 63;
  const int q = lane >> 4, r = lane & 15;        // matvec frag coords; also epilogue q3/r3
  const int j0 = blockIdx.x * 16;
  float* hlast = out + (size_t)B_ * T_ * H_;

  // B-frags resident in VGPRs: Wreg[g][ks] lane(q,r) = W[g*1024+j0+r][w*128+ks*32+q*8 ..+8]
  s16x8 Wreg[3][4];
#pragma unroll
  for (int g = 0; g < 3; ++g)
#pragma unroll
    for (int ks = 0; ks < 4; ++ks)
      Wreg[g][ks] = *(const s16x8*)(whh + ((size_t)(g * 1024 + j0 + r)) * 1024 + w * 128 + ks * 32 + q * 8);

  // epilogue: lane owns cells (b0+e, c=j0+r), e in {0,1}; b0 = w*8 + q*2
  const int b0 = w * 8 + q * 2;
  const float bh0 = bhh[j0 + r];
  const float bh1 = bhh[1024 + j0 + r];
  const float bh2 = bhh[2048 + j0 + r];
  float hreg[2];
  hreg[0] = hchk[(size_t)b0 * 1024 + j0 + r];
  hreg[1] = hchk[(size_t)(b0 + 1) * 1024 + j0 + r];

  f32x4 acc[3][4] = {};
  float gcur[6], gnxt[6], mcur[2], mnxt[2], mncur[2], mnnxt[2];
#pragma unroll
  for (int e = 0; e < 2; ++e) {  // preload tl=0
    size_t mrow = (size_t)(b0 + e) * 3072;
    gcur[e * 3 + 0] = bf2f(gi[mrow + j0 + r]);
    gcur[e * 3 + 1] = bf2f(gi[mrow + 1024 + j0 + r]);
    gcur[e * 3 + 2] = bf2f(gi[mrow + 2048 + j0 + r]);
    mcur[e] = maskT[t0 * 64 + b0 + e];
    int tn = (t0 + 1 < 512) ? t0 + 1 : 511;
    mncur[e] = maskT[tn * 64 + b0 + e];
  }

  for (int tl = 0; tl < TC_; ++tl) {
    const int t = t0 + tl;
    const unsigned short* hsT = hb16T + (size_t)(t & 1) * 65536;
    unsigned short* hdT = hb16T + (size_t)((t + 1) & 1) * 65536;

    // 1) stage tiled h into LDS: 128 x 1KB chunks, wave-uniform LDS dst + per-lane src
    for (int c = w; c < 128; c += 8)
      g2l16(hsT + c * 512 + lane * 8, lds_h + c * 512);
    __syncthreads();  // drains vmcnt: staging complete

    // 2) matvec: A-frag (row=bt*16+r, k=q*8 within 32-k tile) x Wreg -> acc[g][bt]
#pragma unroll
    for (int ks = 0; ks < 4; ++ks) {
      s16x8 a[4];
#pragma unroll
      for (int bt = 0; bt < 4; ++bt)
        a[bt] = *(const s16x8*)&lds_h[((bt * 32 + w * 4 + ks) << 9) + r * 32 + q * 8];
#pragma unroll
      for (int g = 0; g < 3; ++g)
#pragma unroll
        for (int bt = 0; bt < 4; ++bt)
          acc[g][bt] = __builtin_amdgcn_mfma_f32_16x16x32_bf16(a[bt], Wreg[g][ks], acc[g][bt], 0, 0, 0);
    }
    __syncthreads();  // all lds_h reads done before red overwrite (alias!)

    // 3) write kp-partials: acc[g][bt] ~ cells (b=bt*16+q*4+reg, c=r)
#pragma unroll
    for (int g = 0; g < 3; ++g)
#pragma unroll
      for (int bt = 0; bt < 4; ++bt) {
        *(f32x4*)&red[(size_t)((g * 8 + w) * 16 + r) * 68 + bt * 16 + q * 4] = acc[g][bt];
        acc[g][bt] = (f32x4){0.f, 0.f, 0.f, 0.f};
      }
    __syncthreads();

    // 4) epilogue: sum over kp, gate math, store next-step (pre-masked) bf16 h
    f32x2 ps[3];
#pragma unroll
    for (int g = 0; g < 3; ++g) {
      f32x2 s = {0.f, 0.f};
#pragma unroll
      for (int kp = 0; kp < 8; ++kp)
        s += *(const f32x2*)&red[(size_t)((g * 8 + kp) * 16 + r) * 68 + b0];
      ps[g] = s;
    }
    float hn2[2];
#pragma unroll
    for (int e = 0; e < 2; ++e) {
      int b = b0 + e;
      float ghr = ps[0][e] + bh0;
      float ghz = ps[1][e] + bh1;
      float ghn = ps[2][e] + bh2;
      float rr = 1.f / (1.f + __expf(-(gcur[e * 3 + 0] + ghr)));
      float zz = 1.f / (1.f + __expf(-(gcur[e * 3 + 1] + ghz)));
      float nn = tanhf(gcur[e * 3 + 2] + rr * ghn);
      float hp = hreg[e] * mcur[e];
      float hn = (1.f - zz) * nn + zz * hp;
      hreg[e] = hn;
      hn2[e] = hn;
      // pre-masked bf16 h for next step's matvec (mask folded at the source)
      unsigned short hv = (mncur[e] == 0.f) ? (unsigned short)0 : f2bf(hn);
      hdT[haddr(b, j0 + r)] = hv;
    }
    __syncthreads();  // drain hdT stores (all waves) to L2 before release

    // 5) arrive (release writes back L2 so other XCDs see hdT)
    if (tid == 0) {
      unsigned tgt = (unsigned)(t + 1);
      unsigned old = __hip_atomic_fetch_add(bar, 1u, __ATOMIC_RELEASE, __HIP_MEMORY_SCOPE_AGENT);
      if (old == 64u * tgt - 1u)
        __hip_atomic_store(flag, tgt, __ATOMIC_RELEASE, __HIP_MEMORY_SCOPE_AGENT);
    }

    // 6) overlap barrier skew/spin: out stores + chunk-boundary stores + next-step prefetch
#pragma unroll
    for (int e = 0; e < 2; ++e) {
      int b = b0 + e;
      out[((size_t)b * 512 + t) * 1024 + j0 + r] = hn2[e];
      if (t == 511) hlast[(size_t)b * 1024 + j0 + r] = hn2[e];
      if (tl == TC_ - 1) hchk[(size_t)b * 1024 + j0 + r] = hn2[e];
    }
    if (tl + 1 < TC_) {  // gi/maskT are immutable during the kernel: stale-cache safe
#pragma unroll
      for (int e = 0; e < 2; ++e) {
        size_t mrow = (size_t)((tl + 1) * 64 + b0 + e) * 3072;
        gnxt[e * 3 + 0] = bf2f(gi[mrow + j0 + r]);
        gnxt[e * 3 + 1] = bf2f(gi[mrow + 1024 + j0 + r]);
        gnxt[e * 3 + 2] = bf2f(gi[mrow + 2048 + j0 + r]);
        mnxt[e] = maskT[(t + 1) * 64 + b0 + e];
        int tn = (t + 2 < 512) ? t + 2 : 511;
        mnnxt[e] = maskT[tn * 64 + b0 + e];
      }
    }

    // 7) wait + acquire (invalidate L2 before reading remote hdT next step)
    if (tid == 0) {
      while (__hip_atomic_load(flag, __ATOMIC_RELAXED, __HIP_MEMORY_SCOPE_AGENT) < (unsigned)(t + 1))
        __builtin_amdgcn_s_sleep(1);
      (void)__hip_atomic_load(bar, __ATOMIC_ACQUIRE, __HIP_MEMORY_SCOPE_AGENT);
    }
    __syncthreads();

#pragma unroll
    for (int e = 0; e < 2; ++e) {
      gcur[e * 3 + 0] = gnxt[e * 3 + 0];
      gcur[e * 3 + 1] = gnxt[e * 3 + 1];
      gcur[e * 3 + 2] = gnxt[e * 3 + 2];
      mcur[e] = mnxt[e];
      mncur[e] = mnnxt[e];
    }
  }
}

extern "C" void kernel_launch(void* const* d_in, const int* in_sizes, int n_in,
                              void* d_out, int out_size, void* d_ws, size_t ws_size,
                              hipStream_t stream) {
  const float* x     = (const float*)d_in[0];
  const float* h0    = (const float*)d_in[1];
  const int*   dones = (const int*)d_in[2];
  const float* Wih   = (const float*)d_in[3];
  const float* Whh   = (const float*)d_in[4];
  const float* bih   = (const float*)d_in[5];
  const float* bhh   = (const float*)d_in[6];
  float* out = (float*)d_out;
  char* ws = (char*)d_ws;
  // ws layout:
  unsigned short* wih_b = (unsigned short*)(ws);                  //  6 MB   [0, 6291456)
  unsigned short* whh_b = (unsigned short*)(ws + 6291456);        //  6 MB   [6291456, 12582912)
  unsigned short* xt_c  = (unsigned short*)(ws + 12582912);       // 16 MB   [12582912, 29360128)
  unsigned short* gi_c  = (unsigned short*)(ws + 29360128);       // 48 MB   [29360128, 79691776)
  float*          maskT = (float*)(ws + 79691776);                // 128 KB  [79691776, 79822848)
  unsigned short* hb16T = (unsigned short*)(ws + 79822848);       // 256 KB  tiled h double buffer
  float*          hchk  = (float*)(ws + 80085248);                // 256 KB  [80085248, 80347392)
  unsigned int*   bar   = (unsigned int*)(ws + 80347392);         // 4 B  barrier counter
  unsigned int*   flag  = (unsigned int*)(ws + 80347520);         // 4 B  release flag (separate line)

  k_cvt_w<<<3072, 256, 0, stream>>>(Wih, wih_b, Whh, whh_b);
  k_misc<<<256, 256, 0, stream>>>(h0, dones, hb16T, hchk, maskT, bar, flag);

  for (int c = 0; c < 4; ++c) {
    int t0 = c * TC_;
    k_xt<<<TC_ * 64, 256, 0, stream>>>(x, xt_c, t0);
    k_gemm<<<dim3(24, TC_ * 64 / 128), 256, 0, stream>>>(xt_c, wih_b, bih, gi_c);
    void* args[] = {(void*)&whh_b, (void*)&bhh, (void*)&gi_c, (void*)&maskT,
                    (void*)&hb16T, (void*)&hchk, (void*)&out, (void*)&bar, (void*)&flag, (void*)&t0};
    hipLaunchCooperativeKernel((const void*)k_gru, dim3(64), dim3(512), args, 0, stream);
  }
}